// Round 2
// baseline (61.358 us; speedup 1.0000x reference)
//
#include <hip/hip_runtime.h>
#include <hip/hip_bf16.h>
#include <stdint.h>

// Problem constants
#define B_DIM 8
#define T_DIM 2048
#define INNER 256      // IN_DIM == HEAD_TOTAL == 256
#define NEGV (-1e9f)
#define SCALE 0.0625f  // 1/sqrt(256)

typedef __bf16 bf16_t;
typedef __bf16 bf16x4_t __attribute__((ext_vector_type(4)));
typedef __bf16 bf16x8 __attribute__((ext_vector_type(8)));
typedef float f32x4 __attribute__((ext_vector_type(4)));

// ---- Kernel 0: fp32 -> bf16 convert (vectorized, grid-stride) ----
__global__ __launch_bounds__(256) void cvt_kernel(
    const float* __restrict__ src, bf16_t* __restrict__ dst, int n4) {
  int i = blockIdx.x * 256 + threadIdx.x;
  const int stride = gridDim.x * 256;
  for (; i < n4; i += stride) {
    f32x4 v = *(const f32x4*)&src[(size_t)i * 4];
    bf16x4_t o;
    o[0] = (bf16_t)v[0]; o[1] = (bf16_t)v[1];
    o[2] = (bf16_t)v[2]; o[3] = (bf16_t)v[3];
    *(bf16x4_t*)&dst[(size_t)i * 4] = o;
  }
}

// ---- async global->LDS, 16B per lane (global_load_lds_dwordx4) ----
__device__ inline void gload_lds16(const bf16_t* g, bf16_t* lds) {
  __builtin_amdgcn_global_load_lds(
      (__attribute__((address_space(1))) void*)(g),
      (__attribute__((address_space(3))) void*)(lds),
      16, 0, 0);
}

// Stage a 128x64 bf16 tile (row stride ldg elements) into lds[128][64].
// Linear LDS layout; wave-uniform LDS base + lane*16 (HW requirement).
__device__ inline void stage_tile(const bf16_t* gbase, int ldg,
                                  bf16_t (*lds)[64], int tid) {
  const int l = tid & 63;
  const int w = tid >> 6;
  const int sub = l >> 3;        // row within 8-row chunk
  const int ce = (l & 7) * 8;    // starting column element (8 bf16 = 16B)
#pragma unroll
  for (int i = 0; i < 4; ++i) {
    const int chunk = i * 4 + w;               // 0..15, uniform per wave
    const int row = chunk * 8 + sub;
    gload_lds16(gbase + (size_t)row * ldg + ce, &lds[chunk * 8][0]);
  }
}

// 128x128 output tile GEMM, C = A * B^T, both A and Bm are [row][k] bf16,
// K = KDIM, m97 structure (stage -> barrier -> MFMA -> barrier).
// 256 threads = 4 waves in 2x2; each wave owns a 64x64 sub-tile (4x4 frags).
template <int KDIM>
__device__ inline void gemm_bt_128(const bf16_t* A, const bf16_t* Bm, int ld,
                                   bf16_t (*Al)[64], bf16_t (*Bl)[64],
                                   f32x4 acc[4][4], int tid) {
  const int l = tid & 63;
  const int wid = tid >> 6;
  const int wr = wid >> 1, wc = wid & 1;
  const int lr = l & 15;   // fragment row (A) / col (B) lane
  const int kg = l >> 4;   // k-chunk group 0..3
#pragma unroll
  for (int k0 = 0; k0 < KDIM; k0 += 64) {
    stage_tile(A + k0, ld, Al, tid);
    stage_tile(Bm + k0, ld, Bl, tid);
    __syncthreads();   // compiler drains vmcnt(0) before s_barrier
#pragma unroll
    for (int kk = 0; kk < 2; ++kk) {
      bf16x8 af[4], bfm[4];
#pragma unroll
      for (int f = 0; f < 4; ++f) {
        af[f]  = *(const bf16x8*)&Al[wr * 64 + f * 16 + lr][kk * 32 + kg * 8];
        bfm[f] = *(const bf16x8*)&Bl[wc * 64 + f * 16 + lr][kk * 32 + kg * 8];
      }
#pragma unroll
      for (int m = 0; m < 4; ++m)
#pragma unroll
        for (int n = 0; n < 4; ++n)
          acc[m][n] = __builtin_amdgcn_mfma_f32_16x16x32_bf16(
              af[m], bfm[n], acc[m][n], 0, 0, 0);
    }
    __syncthreads();
  }
}

// ---- Kernel 1: Q = xb @ Wqb^T, K = xb @ Wkb^T (bf16 out to workspace) ----
__global__ __launch_bounds__(256) void proj_kernel(
    const bf16_t* __restrict__ x, const bf16_t* __restrict__ Wq,
    const bf16_t* __restrict__ Wk, bf16_t* __restrict__ Q,
    bf16_t* __restrict__ Kout) {
  __shared__ bf16_t Al[128][64];
  __shared__ bf16_t Bl[128][64];
  const int tid = threadIdx.x;
  const int mrow = blockIdx.x * 128;   // row in [0, B*T)
  const int ncol = blockIdx.y * 128;   // out-feature
  const bf16_t* W = blockIdx.z ? Wk : Wq;
  bf16_t* O = blockIdx.z ? Kout : Q;

  f32x4 acc[4][4] = {};
  gemm_bt_128<INNER>(x + (size_t)mrow * INNER, W + (size_t)ncol * INNER,
                     INNER, Al, Bl, acc, tid);

  const int l = tid & 63, wid = tid >> 6, wr = wid >> 1, wc = wid & 1;
  const int lr = l & 15, kg = l >> 4;
#pragma unroll
  for (int m = 0; m < 4; ++m)
#pragma unroll
    for (int n = 0; n < 4; ++n)
#pragma unroll
      for (int j = 0; j < 4; ++j) {
        // C/D layout: col = lane&15, row = (lane>>4)*4 + reg  [m89]
        int r = mrow + wr * 64 + m * 16 + kg * 4 + j;
        int c = ncol + wc * 64 + n * 16 + lr;
        O[(size_t)r * INNER + c] = (bf16_t)acc[m][n][j];
      }
}

// ---- Kernel 2: E = Q @ K^T * scale + mask (fp32 out) ----
__global__ __launch_bounds__(256) void scores_kernel(
    const bf16_t* __restrict__ Q, const bf16_t* __restrict__ Kin,
    float* __restrict__ E) {
  const int ct = blockIdx.x;   // col tile (s)
  const int rt = blockIdx.y;   // row tile (t)
  const int b = blockIdx.z;
  const int tid = threadIdx.x;
  float* Eb = E + (size_t)b * T_DIM * T_DIM;
  const int trow = rt * 128, scol = ct * 128;

  if (ct < rt) {
    // strictly below diagonal: every element masked -> exact -1e9 fill
    f32x4 neg = {NEGV, NEGV, NEGV, NEGV};
#pragma unroll
    for (int it = 0; it < 16; ++it) {
      int idx = it * 256 + tid;          // 0..4095 float4 slots
      int r = idx >> 5, c4 = idx & 31;
      *(f32x4*)&Eb[(size_t)(trow + r) * T_DIM + scol + c4 * 4] = neg;
    }
    return;
  }

  __shared__ bf16_t Al[128][64];
  __shared__ bf16_t Bl[128][64];
  f32x4 acc[4][4] = {};
  const bf16_t* Qb = Q + (size_t)b * T_DIM * INNER;
  const bf16_t* Kb = Kin + (size_t)b * T_DIM * INNER;
  gemm_bt_128<INNER>(Qb + (size_t)trow * INNER, Kb + (size_t)scol * INNER,
                     INNER, Al, Bl, acc, tid);

  const int l = tid & 63, wid = tid >> 6, wr = wid >> 1, wc = wid & 1;
  const int lr = l & 15, kg = l >> 4;
  const bool diag = (ct == rt);
#pragma unroll
  for (int m = 0; m < 4; ++m)
#pragma unroll
    for (int n = 0; n < 4; ++n)
#pragma unroll
      for (int j = 0; j < 4; ++j) {
        int t = trow + wr * 64 + m * 16 + kg * 4 + j;
        int s = scol + wc * 64 + n * 16 + lr;
        float v = acc[m][n][j] * SCALE;
        if (diag && s < t) v += NEGV;
        Eb[(size_t)t * T_DIM + s] = v;
      }
}

extern "C" void kernel_launch(void* const* d_in, const int* in_sizes, int n_in,
                              void* d_out, int out_size, void* d_ws,
                              size_t ws_size, hipStream_t stream) {
  const float* x  = (const float*)d_in[0];   // [8,2048,256] fp32
  const float* Wq = (const float*)d_in[1];   // [256,256] fp32
  const float* Wk = (const float*)d_in[2];   // [256,256] fp32
  float* out = (float*)d_out;

  const size_t n_x = (size_t)B_DIM * T_DIM * INNER;  // 4,194,304
  const size_t n_w = (size_t)INNER * INNER;          // 65,536

  // Workspace layout (bf16): xb | Wqb | Wkb | Q | K  (~25.4 MB)
  bf16_t* xb  = (bf16_t*)d_ws;
  bf16_t* Wqb = xb + n_x;
  bf16_t* Wkb = Wqb + n_w;
  bf16_t* Q   = Wkb + n_w;
  bf16_t* K   = Q + n_x;

  // fp32 -> bf16 converts
  cvt_kernel<<<2048, 256, 0, stream>>>(x, xb, (int)(n_x / 4));
  cvt_kernel<<<64, 256, 0, stream>>>(Wq, Wqb, (int)(n_w / 4));
  cvt_kernel<<<64, 256, 0, stream>>>(Wk, Wkb, (int)(n_w / 4));

  dim3 g1(B_DIM * T_DIM / 128, INNER / 128, 2);  // (128, 2, 2)
  proj_kernel<<<g1, dim3(256), 0, stream>>>(xb, Wqb, Wkb, Q, K);

  dim3 g2(T_DIM / 128, T_DIM / 128, B_DIM);      // (16, 16, 8)
  scores_kernel<<<g2, dim3(256), 0, stream>>>(Q, K, out);
}